// Round 5
// baseline (139.963 us; speedup 1.0000x reference)
//
#include <hip/hip_runtime.h>
#include <hip/hip_bf16.h>

// Problem constants (fixed by setup_inputs)
constexpr int B  = 2;
constexpr int C  = 256;       // channels per level
constexpr int H0 = 100, W0 = 152;
constexpr int H1 = 50,  W1 = 76;
constexpr int H2 = 25,  W2 = 38;
constexpr int N  = 128;       // rois per batch
constexpr int K  = B * N;     // 256 rois
constexpr int CT = 3 * C;     // 768 fused channels
constexpr int OUTS = 7;       // output grid

#define DEV __device__ __forceinline__

DEV float ldbf(const __hip_bfloat16* p) { return __bfloat162float(*p); }

// pack 4 channels -> 8B store
DEV void st4bf(__hip_bfloat16* p, float a, float b, float c, float d) {
  union { __hip_bfloat16 h[4]; uint2 u; } pk;
  pk.h[0] = __float2bfloat16(a); pk.h[1] = __float2bfloat16(b);
  pk.h[2] = __float2bfloat16(c); pk.h[3] = __float2bfloat16(d);
  *reinterpret_cast<uint2*>(p) = pk.u;
}

// ---------------------------------------------------------------------------
// Kernel 1: fused upsample + concat + NCHW->BHWC transpose, bf16 feat.
// Block = (b, y, tile); tile in [0,12): level = tile>>2, 64-channel slice.
// Level 0: float4-coalesced transpose via LDS [64][153].
// Levels 1/2 (separable upsample): load the two source rows coalesced
// (float4 / float2), fuse the y-lerp into an LDS row buffer, then the
// write phase only x-lerps from LDS. Writes are 4-channel packed bf16 (8B).
// ---------------------------------------------------------------------------
__global__ __launch_bounds__(256) void fuse_kernel(
    const float* __restrict__ x0, const float* __restrict__ x1,
    const float* __restrict__ x2, __hip_bfloat16* __restrict__ feat) {
  __shared__ float buf[64 * 153];   // 39.2 KB (level 0 worst case)
  const int blk  = blockIdx.x;
  const int tile = blk % 12;
  const int by   = blk / 12;
  const int y    = by % H0;
  const int b    = by / H0;
  const int t    = threadIdx.x;
  const int level = tile >> 2;          // 0: x0 copy, 1: up(x1), 2: up(x2)
  const int c0l   = (tile & 3) * 64;    // channel base within level

  __hip_bfloat16* const orow =
      feat + (((size_t)b * H0 + y) * W0) * CT + tile * 64;

  if (level == 0) {
    // ---- pure transpose: 64 ch x 38 float4 coalesced loads ----
    const float* src = x0 + (((size_t)b * C + c0l) * H0 + y) * W0;
    for (int i = 0; i < 10; ++i) {
      const int lin = i * 256 + t;
      if (lin < 2432) {
        const int cl = lin / 38, xq = lin % 38;
        const float4 v =
            *reinterpret_cast<const float4*>(src + (size_t)cl * (H0 * W0) + xq * 4);
        float* d = &buf[cl * 153 + xq * 4];
        d[0] = v.x; d[1] = v.y; d[2] = v.z; d[3] = v.w;
      }
    }
    __syncthreads();
    for (int i = 0; i < 10; ++i) {
      const int lin = i * 256 + t;
      if (lin < 2432) {
        const int x = lin >> 4, cq = lin & 15;
        st4bf(orow + (size_t)x * CT + cq * 4,
              buf[(cq * 4 + 0) * 153 + x], buf[(cq * 4 + 1) * 153 + x],
              buf[(cq * 4 + 2) * 153 + x], buf[(cq * 4 + 3) * 153 + x]);
      }
    }
  } else if (level == 1) {
    // ---- 2x upsample: src = (dst+0.5)*0.5 - 0.5, edge-clamped ----
    const float fy = fminf(fmaxf(y * 0.5f - 0.25f, 0.f), (float)(H1 - 1));
    const int   y0i = (int)fy;
    const float ly  = fy - (float)y0i;
    const int   y1i = min(y0i + 1, H1 - 1);
    const int rstep = (y1i - y0i) * W1;
    const float* s0 = x1 + (((size_t)b * C + c0l) * H1 + y0i) * W1;
    // 64 ch x 19 float4 = 1216 units; fuse y-lerp into LDS row buffer
    for (int i = 0; i < 5; ++i) {
      const int lin = i * 256 + t;
      if (lin < 1216) {
        const int cl = lin / 19, xq = lin % 19;
        const float* p = s0 + (size_t)cl * (H1 * W1) + xq * 4;
        const float4 v0 = *reinterpret_cast<const float4*>(p);
        const float4 v1 = *reinterpret_cast<const float4*>(p + rstep);
        float* d = &buf[cl * 81 + xq * 4];
        d[0] = v0.x + ly * (v1.x - v0.x);
        d[1] = v0.y + ly * (v1.y - v0.y);
        d[2] = v0.z + ly * (v1.z - v0.z);
        d[3] = v0.w + ly * (v1.w - v0.w);
      }
    }
    __syncthreads();
    for (int i = 0; i < 10; ++i) {
      const int lin = i * 256 + t;
      if (lin < 2432) {
        const int x = lin >> 4, cq = lin & 15;
        const float fx = fminf(fmaxf(x * 0.5f - 0.25f, 0.f), (float)(W1 - 1));
        const int   x0i = (int)fx;
        const float lx  = fx - (float)x0i;
        const int   x1i = min(x0i + 1, W1 - 1);
        const float* r = &buf[cq * 4 * 81];
        float v[4];
        #pragma unroll
        for (int j = 0; j < 4; ++j) {
          const float a = r[j * 81 + x0i], bb = r[j * 81 + x1i];
          v[j] = a + lx * (bb - a);
        }
        st4bf(orow + (size_t)x * CT + cq * 4, v[0], v[1], v[2], v[3]);
      }
    }
  } else {
    // ---- 4x upsample: src = (dst+0.5)*0.25 - 0.5, edge-clamped ----
    const float fy = fminf(fmaxf(y * 0.25f - 0.375f, 0.f), (float)(H2 - 1));
    const int   y0i = (int)fy;
    const float ly  = fy - (float)y0i;
    const int   y1i = min(y0i + 1, H2 - 1);
    const int rstep = (y1i - y0i) * W2;
    const float* s0 = x2 + (((size_t)b * C + c0l) * H2 + y0i) * W2;
    // 64 ch x 19 float2 = 1216 units (W2=38 rows are only 8B-aligned)
    for (int i = 0; i < 5; ++i) {
      const int lin = i * 256 + t;
      if (lin < 1216) {
        const int cl = lin / 19, xq = lin % 19;
        const float* p = s0 + (size_t)cl * (H2 * W2) + xq * 2;
        const float2 v0 = *reinterpret_cast<const float2*>(p);
        const float2 v1 = *reinterpret_cast<const float2*>(p + rstep);
        float* d = &buf[cl * 39 + xq * 2];
        d[0] = v0.x + ly * (v1.x - v0.x);
        d[1] = v0.y + ly * (v1.y - v0.y);
      }
    }
    __syncthreads();
    for (int i = 0; i < 10; ++i) {
      const int lin = i * 256 + t;
      if (lin < 2432) {
        const int x = lin >> 4, cq = lin & 15;
        const float fx = fminf(fmaxf(x * 0.25f - 0.375f, 0.f), (float)(W2 - 1));
        const int   x0i = (int)fx;
        const float lx  = fx - (float)x0i;
        const int   x1i = min(x0i + 1, W2 - 1);
        const float* r = &buf[cq * 4 * 39];
        float v[4];
        #pragma unroll
        for (int j = 0; j < 4; ++j) {
          const float a = r[j * 39 + x0i], bb = r[j * 39 + x1i];
          v[j] = a + lx * (bb - a);
        }
        st4bf(orow + (size_t)x * CT + cq * 4, v[0], v[1], v[2], v[3]);
      }
    }
  }
}

// ---------------------------------------------------------------------------
// Kernel 2: RoIAlign from bf16 BHWC feat. Block = (k, cgroup); 768 blocks.
// Thread t owns channel cg*256+t for ALL 49 output cells of roi k.
// NEW: per (ph, iy, channel-slice) all 56 corner loads (14 x-samples x 4
// corners) are batched into fully-unrolled register arrays BEFORE the FMAs
// -> 56 outstanding loads/wave (was ~4, vmcnt-serialized at VGPR_Count=36).
// LDS 50.2KB -> 3 blocks/CU = 3 waves/SIMD -> VGPR budget 170;
// __launch_bounds__(256,3) targets that.
// ---------------------------------------------------------------------------
__global__ __launch_bounds__(256, 3) void roi_kernel(
    const __hip_bfloat16* __restrict__ feat, const float* __restrict__ boxes,
    const float* __restrict__ ratio, const float* __restrict__ offset,
    const float* __restrict__ shape, float* __restrict__ out) {
  __shared__ float lds[256 * 49];
  const int blk = blockIdx.x;
  const int cg  = blk % 3;
  const int k   = blk / 3;
  const int b   = k >> 7;      // N = 128
  const int t   = threadIdx.x;
  const int c   = cg * 256 + t;

  // scale factors (batch 0, per reference)
  const float padded_h = floorf(shape[0] * ratio[0] + 2.f * offset[0]);
  const float padded_w = floorf(shape[1] * ratio[1] + 2.f * offset[1]);
  const float sx = (float)W0 / padded_w;
  const float sy = (float)H0 / padded_h;
  // per-batch roi transform
  const float rHb = ratio[b * 2 + 0], rWb = ratio[b * 2 + 1];
  const float topb = offset[b * 2 + 0], leftb = offset[b * 2 + 1];
  const float* bx = boxes + (size_t)k * 4;
  const float x1s = (bx[0] * rWb + leftb) * sx;
  const float y1s = (bx[1] * rHb + topb) * sy;
  const float x2s = (bx[2] * rWb + leftb) * sx;
  const float y2s = (bx[3] * rHb + topb) * sy;
  const float bw = fmaxf(x2s - x1s, 1.f) / OUTS;
  const float bh = fmaxf(y2s - y1s, 1.f) / OUTS;

  // hoisted x-sample data: 14 samples, validity folded into weights
  float hx[14], lx[14];
  int xo0[14], xo1[14];
  #pragma unroll
  for (int s = 0; s < 14; ++s) {
    const float X = x1s + ((float)s * 0.5f + 0.25f) * bw;
    const bool vx = (X >= -1.f) && (X <= (float)W0);
    const float Xc = fminf(fmaxf(X, 0.f), (float)(W0 - 1));
    const float xf = floorf(Xc);
    const float l  = Xc - xf;
    const int x0i = (int)xf;
    const int x1i = min(x0i + 1, W0 - 1);
    hx[s]  = vx ? (1.f - l) : 0.f;
    lx[s]  = vx ? l : 0.f;
    xo0[s] = x0i * CT;
    xo1[s] = x1i * CT;
  }

  const __hip_bfloat16* fb = feat + (size_t)b * (H0 * W0 * CT) + c;

  for (int ph = 0; ph < OUTS; ++ph) {
    float acc[OUTS] = {0.f, 0.f, 0.f, 0.f, 0.f, 0.f, 0.f};
    #pragma unroll
    for (int iy = 0; iy < 2; ++iy) {
      const float Y = y1s + ((float)ph + (float)iy * 0.5f + 0.25f) * bh;
      const bool vy = (Y >= -1.f) && (Y <= (float)H0);
      const float Yc = fminf(fmaxf(Y, 0.f), (float)(H0 - 1));
      const float yf = floorf(Yc);
      const float ly = Yc - yf;
      const int y0i = (int)yf;
      const int y1i = min(y0i + 1, H0 - 1);
      const float w0 = vy ? (1.f - ly) * 0.25f : 0.f;  // fold mean /4 + vy
      const float w1 = vy ? ly * 0.25f : 0.f;
      const __hip_bfloat16* r0 = fb + (size_t)y0i * (W0 * CT);
      const __hip_bfloat16* r1 = fb + (size_t)y1i * (W0 * CT);
      // batch all 56 independent loads into registers, then FMA
      float v00[14], v01[14], v10[14], v11[14];
      #pragma unroll
      for (int s = 0; s < 14; ++s) {
        v00[s] = ldbf(r0 + xo0[s]);
        v01[s] = ldbf(r0 + xo1[s]);
        v10[s] = ldbf(r1 + xo0[s]);
        v11[s] = ldbf(r1 + xo1[s]);
      }
      #pragma unroll
      for (int s = 0; s < 14; ++s) {
        acc[s >> 1] += w0 * (hx[s] * v00[s] + lx[s] * v01[s]) +
                       w1 * (hx[s] * v10[s] + lx[s] * v11[s]);
      }
    }
    #pragma unroll
    for (int pw = 0; pw < OUTS; ++pw) lds[t * 49 + ph * 7 + pw] = acc[pw];
  }
  __syncthreads();
  // contiguous 50176B block write: 12544 floats = 3136 float4
  float* ob = out + (size_t)k * (CT * 49) + (size_t)cg * (256 * 49);
  const float4* ls = reinterpret_cast<const float4*>(lds);
  float4* os = reinterpret_cast<float4*>(ob);
  for (int i = 0; i < 13; ++i) {
    const int idx = i * 256 + t;
    if (idx < 3136) os[idx] = ls[idx];
  }
}

extern "C" void kernel_launch(void* const* d_in, const int* in_sizes, int n_in,
                              void* d_out, int out_size, void* d_ws, size_t ws_size,
                              hipStream_t stream) {
  const float* x0     = (const float*)d_in[0];
  const float* x1     = (const float*)d_in[1];
  const float* x2     = (const float*)d_in[2];
  const float* boxes  = (const float*)d_in[3];
  const float* ratio  = (const float*)d_in[4];
  const float* offset = (const float*)d_in[5];
  const float* shape  = (const float*)d_in[6];
  float* out = (float*)d_out;

  __hip_bfloat16* feat = (__hip_bfloat16*)d_ws;  // 46.7 MB, fits ws
  const dim3 blk(256);
  const dim3 g1(B * H0 * 12);
  const dim3 g2(K * 3);

  fuse_kernel<<<g1, blk, 0, stream>>>(x0, x1, x2, feat);
  roi_kernel<<<g2, blk, 0, stream>>>(feat, boxes, ratio, offset, shape, out);
}